// Round 1
// baseline (412.472 us; speedup 1.0000x reference)
//
#include <hip/hip_runtime.h>
#include <math.h>

// Problem dims
#define NB    2
#define LSEQ  256
#define HDIM  256
#define IDIM  512
#define NROW  512      // NB*LSEQ
#define ESZ   1536     // effective fused ssm/gate output cols

// ---------------------------------------------------------------------------
// K1: xp = x @ W_in^T   (512x256 @ 256x1024) -> xq(gelu'd first 512), xk(raw)
// ---------------------------------------------------------------------------
__global__ __launch_bounds__(256) void k1_xp(const float* __restrict__ x,
                                             const float* __restrict__ W_in,
                                             float* __restrict__ xq,
                                             float* __restrict__ xk) {
    __shared__ float As[32][65];
    __shared__ float Bs[32][65];
    const int r0 = blockIdx.y * 64;
    const int o0 = blockIdx.x * 64;
    const int t = threadIdx.x;
    const int tx = t & 15, ty = t >> 4;
    float acc[4][4] = {};
    for (int k0 = 0; k0 < 256; k0 += 32) {
        #pragma unroll
        for (int q = 0; q < 8; ++q) {
            int idx = t + q * 256;
            int m = idx >> 5, kk = idx & 31;
            As[kk][m] = x[(r0 + m) * 256 + k0 + kk];
            Bs[kk][m] = W_in[(o0 + m) * 256 + k0 + kk];
        }
        __syncthreads();
        #pragma unroll
        for (int kk = 0; kk < 32; ++kk) {
            float a[4], b[4];
            #pragma unroll
            for (int m = 0; m < 4; ++m) a[m] = As[kk][ty * 4 + m];
            #pragma unroll
            for (int n = 0; n < 4; ++n) b[n] = Bs[kk][tx * 4 + n];
            #pragma unroll
            for (int m = 0; m < 4; ++m)
                #pragma unroll
                for (int n = 0; n < 4; ++n) acc[m][n] += a[m] * b[n];
        }
        __syncthreads();
    }
    #pragma unroll
    for (int m = 0; m < 4; ++m)
        #pragma unroll
        for (int n = 0; n < 4; ++n) {
            int r = r0 + ty * 4 + m, o = o0 + tx * 4 + n;
            float v = acc[m][n];
            if (o < IDIM) {
                xq[r * IDIM + o] = 0.5f * v * (1.0f + erff(v * 0.70710678118654752f));
            } else {
                xk[r * IDIM + (o - IDIM)] = v;
            }
        }
}

// ---------------------------------------------------------------------------
// K2: xc[r,o] = gelu_xq[r,o] + conv_b[o] + sum_{i,k} conv_w[o,i,k]*xk[r+k-1,i]
//     (zero pad at per-batch sequence boundaries)
// ---------------------------------------------------------------------------
__global__ __launch_bounds__(256) void k2_conv(const float* __restrict__ xk,
                                               const float* __restrict__ conv_w,
                                               const float* __restrict__ conv_b,
                                               const float* __restrict__ xq,
                                               float* __restrict__ xc) {
    __shared__ float Xs[66][33];       // window rows r0-1 .. r0+64
    __shared__ float Ws[64 * 97];      // [o][i*3+k], padded stride 97
    const int r0 = blockIdx.y * 64;
    const int o0 = blockIdx.x * 64;
    const int t = threadIdx.x;
    const int tx = t & 15, ty = t >> 4;
    const int bb = r0 >> 8;            // batch index (tiles never cross batch)
    const int lo = bb * LSEQ, hi = lo + LSEQ;
    float acc[4][4] = {};
    for (int i0 = 0; i0 < IDIM; i0 += 32) {
        for (int idx = t; idx < 66 * 32; idx += 256) {
            int m = idx >> 5, ii = idx & 31;
            int g = r0 - 1 + m;
            Xs[m][ii] = (g >= lo && g < hi) ? xk[g * IDIM + i0 + ii] : 0.0f;
        }
        for (int idx = t; idx < 64 * 96; idx += 256) {
            int o = idx / 96, rem = idx % 96;   // rem = i*3+k
            int i = rem / 3, k = rem % 3;
            Ws[o * 97 + rem] = conv_w[((size_t)(o0 + o) * IDIM + i0 + i) * 3 + k];
        }
        __syncthreads();
        #pragma unroll
        for (int ii = 0; ii < 32; ++ii) {
            float a[6];
            #pragma unroll
            for (int m = 0; m < 6; ++m) a[m] = Xs[ty * 4 + m][ii];
            #pragma unroll
            for (int n = 0; n < 4; ++n) {
                const float* wp = &Ws[(tx * 4 + n) * 97 + ii * 3];
                float w0 = wp[0], w1 = wp[1], w2 = wp[2];
                #pragma unroll
                for (int m = 0; m < 4; ++m)
                    acc[m][n] += a[m] * w0 + a[m + 1] * w1 + a[m + 2] * w2;
            }
        }
        __syncthreads();
    }
    #pragma unroll
    for (int m = 0; m < 4; ++m)
        #pragma unroll
        for (int n = 0; n < 4; ++n) {
            int r = r0 + ty * 4 + m, o = o0 + tx * 4 + n;
            xc[r * IDIM + o] = acc[m][n] + conv_b[o] + xq[r * IDIM + o];
        }
}

// ---------------------------------------------------------------------------
// K3: E[r,j] for j in [0,1536): fused {C_raw, D_w, gate_raw} GEMM over xc
//   j<1024  -> W_ssm row (512+j), bias b_ssm[512+j]
//   j>=1024 -> W_gate row (j-512), bias b_gate[j-512]
// ---------------------------------------------------------------------------
__global__ __launch_bounds__(256) void k3_gemm(const float* __restrict__ xc,
                                               const float* __restrict__ W_ssm,
                                               const float* __restrict__ b_ssm,
                                               const float* __restrict__ W_gate,
                                               const float* __restrict__ b_gate,
                                               float* __restrict__ E) {
    __shared__ float As[32][65];
    __shared__ float Bs[32][65];
    const int r0 = blockIdx.y * 64;
    const int j0 = blockIdx.x * 64;
    const int t = threadIdx.x;
    const int tx = t & 15, ty = t >> 4;
    float acc[4][4] = {};
    for (int k0 = 0; k0 < IDIM; k0 += 32) {
        #pragma unroll
        for (int q = 0; q < 8; ++q) {
            int idx = t + q * 256;
            int m = idx >> 5, kk = idx & 31;
            int jj = j0 + m;
            const float* src = (jj < 1024) ? (W_ssm + (size_t)(512 + jj) * IDIM)
                                           : (W_gate + (size_t)(jj - 512) * IDIM);
            Bs[kk][m] = src[k0 + kk];
            As[kk][m] = xc[(r0 + m) * IDIM + k0 + kk];
        }
        __syncthreads();
        #pragma unroll
        for (int kk = 0; kk < 32; ++kk) {
            float a[4], b[4];
            #pragma unroll
            for (int m = 0; m < 4; ++m) a[m] = As[kk][ty * 4 + m];
            #pragma unroll
            for (int n = 0; n < 4; ++n) b[n] = Bs[kk][tx * 4 + n];
            #pragma unroll
            for (int m = 0; m < 4; ++m)
                #pragma unroll
                for (int n = 0; n < 4; ++n) acc[m][n] += a[m] * b[n];
        }
        __syncthreads();
    }
    #pragma unroll
    for (int m = 0; m < 4; ++m)
        #pragma unroll
        for (int n = 0; n < 4; ++n) {
            int r = r0 + ty * 4 + m, j = j0 + tx * 4 + n;
            float bias = (j < 1024) ? b_ssm[512 + j] : b_gate[j - 512];
            E[r * ESZ + j] = acc[m][n] + bias;
        }
}

// ---------------------------------------------------------------------------
// K3b: elementwise: Cw[r,s] = sigmoid(E[r,1024+s]) * E[r,s]
//                   u[r,i]  = xc[r,i] * E[r,512+i]^2
// ---------------------------------------------------------------------------
__global__ __launch_bounds__(256) void k3b_elem(const float* __restrict__ E,
                                                const float* __restrict__ xc,
                                                float* __restrict__ Cw,
                                                float* __restrict__ u) {
    int idx = blockIdx.x * 256 + threadIdx.x;   // < 512*512
    int r = idx >> 9, s = idx & 511;
    const float* Er = E + (size_t)r * ESZ;
    float craw = Er[s];
    float dw   = Er[512 + s];
    float graw = Er[1024 + s];
    float g = 1.0f / (1.0f + expf(-graw));
    Cw[idx] = g * craw;
    u[idx]  = xc[idx] * dw * dw;
}

// ---------------------------------------------------------------------------
// K4: scan + contraction over s.
//   h[l,s,i] = A[s,i]*h[l-1,s,i] + u[b,l,s]
//   y[b,l,i] = sum_s Cw[b,l,s]*h[l,s,i] + u[b,l,i]*D[i]
// One wave per (b,i): lane owns 8 s-values in registers; butterfly-reduce per l.
// ---------------------------------------------------------------------------
__global__ __launch_bounds__(256) void k4_scan(const float* __restrict__ u,
                                               const float* __restrict__ Cw,
                                               const float* __restrict__ A,
                                               const float* __restrict__ D,
                                               float* __restrict__ y) {
    const int wave = (blockIdx.x * 256 + threadIdx.x) >> 6;  // 0..1023
    const int lane = threadIdx.x & 63;
    const int b = wave >> 9, i = wave & 511;
    const int s8 = lane * 8;
    float a[8], h[8];
    #pragma unroll
    for (int j = 0; j < 8; ++j) {
        a[j] = A[(size_t)(s8 + j) * IDIM + i];
        h[j] = 0.0f;
    }
    const float Di = D[i];
    const float* ub = u + (size_t)b * LSEQ * IDIM;
    const float* cb = Cw + (size_t)b * LSEQ * IDIM;
    float* yb = y + (size_t)b * LSEQ * IDIM;
    for (int l = 0; l < LSEQ; ++l) {
        const float4* up = (const float4*)(ub + l * IDIM + s8);
        const float4* cp = (const float4*)(cb + l * IDIM + s8);
        float4 u0 = up[0], u1 = up[1];
        float4 c0 = cp[0], c1 = cp[1];
        h[0] = h[0] * a[0] + u0.x; h[1] = h[1] * a[1] + u0.y;
        h[2] = h[2] * a[2] + u0.z; h[3] = h[3] * a[3] + u0.w;
        h[4] = h[4] * a[4] + u1.x; h[5] = h[5] * a[5] + u1.y;
        h[6] = h[6] * a[6] + u1.z; h[7] = h[7] * a[7] + u1.w;
        float p0 = c0.x * h[0] + c0.y * h[1] + c0.z * h[2] + c0.w * h[3];
        float p1 = c1.x * h[4] + c1.y * h[5] + c1.z * h[6] + c1.w * h[7];
        float p = p0 + p1;
        #pragma unroll
        for (int off = 1; off < 64; off <<= 1) p += __shfl_xor(p, off, 64);
        float uli = ub[l * IDIM + i];
        if (lane == 0) yb[l * IDIM + i] = p + uli * Di;
    }
}

// ---------------------------------------------------------------------------
// K5a: outlin = y @ W_out^T   (512x512 @ 512x256)
// ---------------------------------------------------------------------------
__global__ __launch_bounds__(256) void k5a_gemm(const float* __restrict__ y,
                                                const float* __restrict__ W_out,
                                                float* __restrict__ outlin) {
    __shared__ float As[32][65];
    __shared__ float Bs[32][65];
    const int r0 = blockIdx.y * 64;
    const int h0 = blockIdx.x * 64;
    const int t = threadIdx.x;
    const int tx = t & 15, ty = t >> 4;
    float acc[4][4] = {};
    for (int k0 = 0; k0 < IDIM; k0 += 32) {
        #pragma unroll
        for (int q = 0; q < 8; ++q) {
            int idx = t + q * 256;
            int m = idx >> 5, kk = idx & 31;
            As[kk][m] = y[(r0 + m) * IDIM + k0 + kk];
            Bs[kk][m] = W_out[(h0 + m) * IDIM + k0 + kk];
        }
        __syncthreads();
        #pragma unroll
        for (int kk = 0; kk < 32; ++kk) {
            float a[4], b[4];
            #pragma unroll
            for (int m = 0; m < 4; ++m) a[m] = As[kk][ty * 4 + m];
            #pragma unroll
            for (int n = 0; n < 4; ++n) b[n] = Bs[kk][tx * 4 + n];
            #pragma unroll
            for (int m = 0; m < 4; ++m)
                #pragma unroll
                for (int n = 0; n < 4; ++n) acc[m][n] += a[m] * b[n];
        }
        __syncthreads();
    }
    #pragma unroll
    for (int m = 0; m < 4; ++m)
        #pragma unroll
        for (int n = 0; n < 4; ++n) {
            int r = r0 + ty * 4 + m, hh = h0 + tx * 4 + n;
            outlin[r * HDIM + hh] = acc[m][n];
        }
}

// ---------------------------------------------------------------------------
// K5b: LayerNorm over H=256 + z scale + residual. One block per row.
// ---------------------------------------------------------------------------
__global__ __launch_bounds__(256) void k5b_ln(const float* __restrict__ outlin,
                                              const float* __restrict__ x,
                                              const float* __restrict__ z,
                                              const float* __restrict__ ln_g,
                                              const float* __restrict__ ln_b,
                                              float* __restrict__ out) {
    const int r = blockIdx.x;
    const int t = threadIdx.x;
    float v = outlin[(size_t)r * HDIM + t];
    float s1 = v, s2 = v * v;
    #pragma unroll
    for (int off = 1; off < 64; off <<= 1) {
        s1 += __shfl_xor(s1, off, 64);
        s2 += __shfl_xor(s2, off, 64);
    }
    __shared__ float r1[4], r2[4];
    const int w = t >> 6, lane = t & 63;
    if (lane == 0) { r1[w] = s1; r2[w] = s2; }
    __syncthreads();
    float t1 = r1[0] + r1[1] + r1[2] + r1[3];
    float t2 = r2[0] + r2[1] + r2[2] + r2[3];
    float mu = t1 * (1.0f / 256.0f);
    float var = t2 * (1.0f / 256.0f) - mu * mu;
    float inv = rsqrtf(var + 1e-5f);
    float o = (v - mu) * inv * ln_g[t] + ln_b[t];
    out[(size_t)r * HDIM + t] = o * z[0] + x[(size_t)r * HDIM + t];
}

// ---------------------------------------------------------------------------
extern "C" void kernel_launch(void* const* d_in, const int* in_sizes, int n_in,
                              void* d_out, int out_size, void* d_ws, size_t ws_size,
                              hipStream_t stream) {
    const float* x      = (const float*)d_in[0];
    const float* W_in   = (const float*)d_in[1];
    const float* conv_w = (const float*)d_in[2];
    const float* conv_b = (const float*)d_in[3];
    const float* W_ssm  = (const float*)d_in[4];
    const float* b_ssm  = (const float*)d_in[5];
    const float* W_gate = (const float*)d_in[6];
    const float* b_gate = (const float*)d_in[7];
    const float* A      = (const float*)d_in[8];
    const float* D      = (const float*)d_in[9];
    const float* W_out  = (const float*)d_in[10];
    const float* z      = (const float*)d_in[11];
    const float* ln_g   = (const float*)d_in[12];
    const float* ln_b   = (const float*)d_in[13];
    float* out = (float*)d_out;

    float* ws = (float*)d_ws;
    float* xq     = ws;                    // 512*512
    float* xk     = ws + 262144;           // 512*512
    float* xc     = ws + 524288;           // 512*512
    float* E      = ws + 786432;           // 512*1536
    float* Cw     = ws + 1572864;          // 512*512
    float* u      = ws + 1835008;          // 512*512
    float* y      = ws + 2097152;          // 512*512
    float* outlin = ws + 2359296;          // 512*256

    k1_xp   <<<dim3(16, 8), 256, 0, stream>>>(x, W_in, xq, xk);
    k2_conv <<<dim3(8, 8),  256, 0, stream>>>(xk, conv_w, conv_b, xq, xc);
    k3_gemm <<<dim3(24, 8), 256, 0, stream>>>(xc, W_ssm, b_ssm, W_gate, b_gate, E);
    k3b_elem<<<1024, 256, 0, stream>>>(E, xc, Cw, u);
    k4_scan <<<256, 256, 0, stream>>>(u, Cw, A, D, y);
    k5a_gemm<<<dim3(4, 8), 256, 0, stream>>>(y, W_out, outlin);
    k5b_ln  <<<512, 256, 0, stream>>>(outlin, x, z, ln_g, ln_b, out);
}

// Round 2
// 372.920 us; speedup vs baseline: 1.1061x; 1.1061x over previous
//
#include <hip/hip_runtime.h>
#include <math.h>

// Problem dims
#define NB    2
#define LSEQ  256
#define HDIM  256
#define IDIM  512
#define NROW  512      // NB*LSEQ
#define ESZ   1536     // effective fused ssm/gate output cols

// ---------------------------------------------------------------------------
// K1: xp = x @ W_in^T   (512x256 @ 256x1024) -> xq(gelu'd first 512), xk(raw)
// LDS pad 68 so fragment reads are 16B-aligned float4 (ds_read_b128).
// ---------------------------------------------------------------------------
__global__ __launch_bounds__(256) void k1_xp(const float* __restrict__ x,
                                             const float* __restrict__ W_in,
                                             float* __restrict__ xq,
                                             float* __restrict__ xk) {
    __shared__ float As[32][68];
    __shared__ float Bs[32][68];
    const int r0 = blockIdx.y * 64;
    const int o0 = blockIdx.x * 64;
    const int t = threadIdx.x;
    const int tx = t & 15, ty = t >> 4;
    float acc[4][4] = {};
    for (int k0 = 0; k0 < 256; k0 += 32) {
        #pragma unroll
        for (int q = 0; q < 8; ++q) {
            int idx = t + q * 256;
            int m = idx >> 5, kk = idx & 31;
            As[kk][m] = x[(r0 + m) * 256 + k0 + kk];
            Bs[kk][m] = W_in[(o0 + m) * 256 + k0 + kk];
        }
        __syncthreads();
        #pragma unroll
        for (int kk = 0; kk < 32; ++kk) {
            float4 av = *(const float4*)&As[kk][ty * 4];
            float4 bv = *(const float4*)&Bs[kk][tx * 4];
            float a[4] = {av.x, av.y, av.z, av.w};
            float b[4] = {bv.x, bv.y, bv.z, bv.w};
            #pragma unroll
            for (int m = 0; m < 4; ++m)
                #pragma unroll
                for (int n = 0; n < 4; ++n) acc[m][n] += a[m] * b[n];
        }
        __syncthreads();
    }
    const bool isq = (o0 < IDIM);
    #pragma unroll
    for (int m = 0; m < 4; ++m) {
        int r = r0 + ty * 4 + m;
        float4 v;
        float* vp = (float*)&v;
        #pragma unroll
        for (int n = 0; n < 4; ++n) {
            float val = acc[m][n];
            vp[n] = isq ? 0.5f * val * (1.0f + erff(val * 0.70710678118654752f)) : val;
        }
        if (isq) *(float4*)&xq[r * IDIM + o0 + tx * 4] = v;
        else     *(float4*)&xk[r * IDIM + (o0 - IDIM) + tx * 4] = v;
    }
}

// ---------------------------------------------------------------------------
// K2: xc[r,o] = gelu_xq[r,o] + conv_b[o] + sum_{i,k} conv_w[o,i,k]*xk[r+k-1,i]
// Transposed X layout [ii][row] -> float4+float2 window reads; weights as
// three [ii][o] tiles -> float4 reads. 5 LDS issues per 48 FMAs.
// ---------------------------------------------------------------------------
__global__ __launch_bounds__(256) void k2_conv(const float* __restrict__ xk,
                                               const float* __restrict__ conv_w,
                                               const float* __restrict__ conv_b,
                                               const float* __restrict__ xq,
                                               float* __restrict__ xc) {
    __shared__ float Xs[32][72];        // [ii][m], m = 0..65 (rows r0-1..r0+64)
    __shared__ float Ws[3][32][68];     // [k][ii][o]
    const int r0 = blockIdx.y * 64;
    const int o0 = blockIdx.x * 64;
    const int t = threadIdx.x;
    const int tx = t & 15, ty = t >> 4;
    const int bb = r0 >> 8;             // batch (tiles never cross batch)
    const int lo = bb * LSEQ, hi = lo + LSEQ;
    float acc[4][4] = {};
    for (int i0 = 0; i0 < IDIM; i0 += 32) {
        for (int idx = t; idx < 66 * 32; idx += 256) {
            int m = idx >> 5, ii = idx & 31;
            int g = r0 - 1 + m;
            Xs[ii][m] = (g >= lo && g < hi) ? xk[g * IDIM + i0 + ii] : 0.0f;
        }
        for (int idx = t; idx < 64 * 96; idx += 256) {
            int o = idx / 96, rem = idx - o * 96;   // rem = ii*3+k
            int ii = rem / 3, k = rem - ii * 3;
            Ws[k][ii][o] = conv_w[((size_t)(o0 + o) * IDIM + i0 + ii) * 3 + k];
        }
        __syncthreads();
        #pragma unroll
        for (int ii = 0; ii < 32; ++ii) {
            float4 x0 = *(const float4*)&Xs[ii][ty * 4];
            float2 x1 = *(const float2*)&Xs[ii][ty * 4 + 4];
            float xa[6] = {x0.x, x0.y, x0.z, x0.w, x1.x, x1.y};
            float4 w0 = *(const float4*)&Ws[0][ii][tx * 4];
            float4 w1 = *(const float4*)&Ws[1][ii][tx * 4];
            float4 w2 = *(const float4*)&Ws[2][ii][tx * 4];
            float b0[4] = {w0.x, w0.y, w0.z, w0.w};
            float b1[4] = {w1.x, w1.y, w1.z, w1.w};
            float b2[4] = {w2.x, w2.y, w2.z, w2.w};
            #pragma unroll
            for (int m = 0; m < 4; ++m)
                #pragma unroll
                for (int n = 0; n < 4; ++n)
                    acc[m][n] += xa[m] * b0[n] + xa[m + 1] * b1[n] + xa[m + 2] * b2[n];
        }
        __syncthreads();
    }
    #pragma unroll
    for (int m = 0; m < 4; ++m) {
        int r = r0 + ty * 4 + m;
        float4 cb = *(const float4*)&conv_b[o0 + tx * 4];
        float4 gq = *(const float4*)&xq[r * IDIM + o0 + tx * 4];
        float4 v;
        v.x = acc[m][0] + cb.x + gq.x;
        v.y = acc[m][1] + cb.y + gq.y;
        v.z = acc[m][2] + cb.z + gq.z;
        v.w = acc[m][3] + cb.w + gq.w;
        *(float4*)&xc[r * IDIM + o0 + tx * 4] = v;
    }
}

// ---------------------------------------------------------------------------
// K3: E[r,j], j in [0,1536): fused {C_raw, D_w, gate_raw} GEMM over xc
// ---------------------------------------------------------------------------
__global__ __launch_bounds__(256) void k3_gemm(const float* __restrict__ xc,
                                               const float* __restrict__ W_ssm,
                                               const float* __restrict__ b_ssm,
                                               const float* __restrict__ W_gate,
                                               const float* __restrict__ b_gate,
                                               float* __restrict__ E) {
    __shared__ float As[32][68];
    __shared__ float Bs[32][68];
    const int r0 = blockIdx.y * 64;
    const int j0 = blockIdx.x * 64;
    const int t = threadIdx.x;
    const int tx = t & 15, ty = t >> 4;
    float acc[4][4] = {};
    for (int k0 = 0; k0 < IDIM; k0 += 32) {
        #pragma unroll
        for (int q = 0; q < 8; ++q) {
            int idx = t + q * 256;
            int m = idx >> 5, kk = idx & 31;
            int jj = j0 + m;
            const float* src = (jj < 1024) ? (W_ssm + (size_t)(512 + jj) * IDIM)
                                           : (W_gate + (size_t)(jj - 512) * IDIM);
            Bs[kk][m] = src[k0 + kk];
            As[kk][m] = xc[(r0 + m) * IDIM + k0 + kk];
        }
        __syncthreads();
        #pragma unroll
        for (int kk = 0; kk < 32; ++kk) {
            float4 av = *(const float4*)&As[kk][ty * 4];
            float4 bv = *(const float4*)&Bs[kk][tx * 4];
            float a[4] = {av.x, av.y, av.z, av.w};
            float b[4] = {bv.x, bv.y, bv.z, bv.w};
            #pragma unroll
            for (int m = 0; m < 4; ++m)
                #pragma unroll
                for (int n = 0; n < 4; ++n) acc[m][n] += a[m] * b[n];
        }
        __syncthreads();
    }
    const bool iss = (j0 < 1024);
    #pragma unroll
    for (int m = 0; m < 4; ++m) {
        int r = r0 + ty * 4 + m;
        float4 bias = iss ? *(const float4*)&b_ssm[512 + j0 + tx * 4]
                          : *(const float4*)&b_gate[j0 - 512 + tx * 4];
        float4 v;
        v.x = acc[m][0] + bias.x;
        v.y = acc[m][1] + bias.y;
        v.z = acc[m][2] + bias.z;
        v.w = acc[m][3] + bias.w;
        *(float4*)&E[r * ESZ + j0 + tx * 4] = v;
    }
}

// ---------------------------------------------------------------------------
// K3b: Cw[r,s] = sigmoid(E[r,1024+s]) * E[r,s];  u[r,i] = xc[r,i]*E[r,512+i]^2
// ---------------------------------------------------------------------------
__global__ __launch_bounds__(256) void k3b_elem(const float* __restrict__ E,
                                                const float* __restrict__ xc,
                                                float* __restrict__ Cw,
                                                float* __restrict__ u) {
    int idx4 = (blockIdx.x * 256 + threadIdx.x) * 4;  // < 512*512
    int r = idx4 >> 9, s = idx4 & 511;
    const float* Er = E + (size_t)r * ESZ;
    float4 craw = *(const float4*)&Er[s];
    float4 dw   = *(const float4*)&Er[512 + s];
    float4 graw = *(const float4*)&Er[1024 + s];
    float4 xcv  = *(const float4*)&xc[idx4];
    float4 cw, uv;
    cw.x = craw.x / (1.0f + expf(-graw.x));
    cw.y = craw.y / (1.0f + expf(-graw.y));
    cw.z = craw.z / (1.0f + expf(-graw.z));
    cw.w = craw.w / (1.0f + expf(-graw.w));
    uv.x = xcv.x * dw.x * dw.x;
    uv.y = xcv.y * dw.y * dw.y;
    uv.z = xcv.z * dw.z * dw.z;
    uv.w = xcv.w * dw.w * dw.w;
    *(float4*)&Cw[idx4] = cw;
    *(float4*)&u[idx4]  = uv;
}

// ---------------------------------------------------------------------------
// K4: scan + contraction over s. One wave per (b,i); lane owns 8 s-values.
// ---------------------------------------------------------------------------
__global__ __launch_bounds__(256) void k4_scan(const float* __restrict__ u,
                                               const float* __restrict__ Cw,
                                               const float* __restrict__ A,
                                               const float* __restrict__ D,
                                               float* __restrict__ y) {
    const int wave = (blockIdx.x * 256 + threadIdx.x) >> 6;  // 0..1023
    const int lane = threadIdx.x & 63;
    const int b = wave >> 9, i = wave & 511;
    const int s8 = lane * 8;
    float a[8], h[8];
    #pragma unroll
    for (int j = 0; j < 8; ++j) {
        a[j] = A[(size_t)(s8 + j) * IDIM + i];
        h[j] = 0.0f;
    }
    const float Di = D[i];
    const float* ub = u + (size_t)b * LSEQ * IDIM;
    const float* cb = Cw + (size_t)b * LSEQ * IDIM;
    float* yb = y + (size_t)b * LSEQ * IDIM;
    for (int l = 0; l < LSEQ; ++l) {
        const float4* up = (const float4*)(ub + l * IDIM + s8);
        const float4* cp = (const float4*)(cb + l * IDIM + s8);
        float4 u0 = up[0], u1 = up[1];
        float4 c0 = cp[0], c1 = cp[1];
        h[0] = h[0] * a[0] + u0.x; h[1] = h[1] * a[1] + u0.y;
        h[2] = h[2] * a[2] + u0.z; h[3] = h[3] * a[3] + u0.w;
        h[4] = h[4] * a[4] + u1.x; h[5] = h[5] * a[5] + u1.y;
        h[6] = h[6] * a[6] + u1.z; h[7] = h[7] * a[7] + u1.w;
        float p0 = c0.x * h[0] + c0.y * h[1] + c0.z * h[2] + c0.w * h[3];
        float p1 = c1.x * h[4] + c1.y * h[5] + c1.z * h[6] + c1.w * h[7];
        float p = p0 + p1;
        #pragma unroll
        for (int off = 1; off < 64; off <<= 1) p += __shfl_xor(p, off, 64);
        float uli = ub[l * IDIM + i];
        if (lane == 0) yb[l * IDIM + i] = p + uli * Di;
    }
}

// ---------------------------------------------------------------------------
// K5a: outlin = y @ W_out^T   (512x512 @ 512x256)
// ---------------------------------------------------------------------------
__global__ __launch_bounds__(256) void k5a_gemm(const float* __restrict__ y,
                                                const float* __restrict__ W_out,
                                                float* __restrict__ outlin) {
    __shared__ float As[32][68];
    __shared__ float Bs[32][68];
    const int r0 = blockIdx.y * 64;
    const int h0 = blockIdx.x * 64;
    const int t = threadIdx.x;
    const int tx = t & 15, ty = t >> 4;
    float acc[4][4] = {};
    for (int k0 = 0; k0 < IDIM; k0 += 32) {
        #pragma unroll
        for (int q = 0; q < 8; ++q) {
            int idx = t + q * 256;
            int m = idx >> 5, kk = idx & 31;
            As[kk][m] = y[(r0 + m) * IDIM + k0 + kk];
            Bs[kk][m] = W_out[(h0 + m) * IDIM + k0 + kk];
        }
        __syncthreads();
        #pragma unroll
        for (int kk = 0; kk < 32; ++kk) {
            float4 av = *(const float4*)&As[kk][ty * 4];
            float4 bv = *(const float4*)&Bs[kk][tx * 4];
            float a[4] = {av.x, av.y, av.z, av.w};
            float b[4] = {bv.x, bv.y, bv.z, bv.w};
            #pragma unroll
            for (int m = 0; m < 4; ++m)
                #pragma unroll
                for (int n = 0; n < 4; ++n) acc[m][n] += a[m] * b[n];
        }
        __syncthreads();
    }
    #pragma unroll
    for (int m = 0; m < 4; ++m) {
        int r = r0 + ty * 4 + m;
        float4 v;
        v.x = acc[m][0]; v.y = acc[m][1]; v.z = acc[m][2]; v.w = acc[m][3];
        *(float4*)&outlin[r * HDIM + h0 + tx * 4] = v;
    }
}

// ---------------------------------------------------------------------------
// K5b: LayerNorm over H=256 + z scale + residual. One block per row.
// ---------------------------------------------------------------------------
__global__ __launch_bounds__(256) void k5b_ln(const float* __restrict__ outlin,
                                              const float* __restrict__ x,
                                              const float* __restrict__ z,
                                              const float* __restrict__ ln_g,
                                              const float* __restrict__ ln_b,
                                              float* __restrict__ out) {
    const int r = blockIdx.x;
    const int t = threadIdx.x;
    float v = outlin[(size_t)r * HDIM + t];
    float s1 = v, s2 = v * v;
    #pragma unroll
    for (int off = 1; off < 64; off <<= 1) {
        s1 += __shfl_xor(s1, off, 64);
        s2 += __shfl_xor(s2, off, 64);
    }
    __shared__ float r1[4], r2[4];
    const int w = t >> 6, lane = t & 63;
    if (lane == 0) { r1[w] = s1; r2[w] = s2; }
    __syncthreads();
    float t1 = r1[0] + r1[1] + r1[2] + r1[3];
    float t2 = r2[0] + r2[1] + r2[2] + r2[3];
    float mu = t1 * (1.0f / 256.0f);
    float var = t2 * (1.0f / 256.0f) - mu * mu;
    float inv = rsqrtf(var + 1e-5f);
    float o = (v - mu) * inv * ln_g[t] + ln_b[t];
    out[(size_t)r * HDIM + t] = o * z[0] + x[(size_t)r * HDIM + t];
}

// ---------------------------------------------------------------------------
extern "C" void kernel_launch(void* const* d_in, const int* in_sizes, int n_in,
                              void* d_out, int out_size, void* d_ws, size_t ws_size,
                              hipStream_t stream) {
    const float* x      = (const float*)d_in[0];
    const float* W_in   = (const float*)d_in[1];
    const float* conv_w = (const float*)d_in[2];
    const float* conv_b = (const float*)d_in[3];
    const float* W_ssm  = (const float*)d_in[4];
    const float* b_ssm  = (const float*)d_in[5];
    const float* W_gate = (const float*)d_in[6];
    const float* b_gate = (const float*)d_in[7];
    const float* A      = (const float*)d_in[8];
    const float* D      = (const float*)d_in[9];
    const float* W_out  = (const float*)d_in[10];
    const float* z      = (const float*)d_in[11];
    const float* ln_g   = (const float*)d_in[12];
    const float* ln_b   = (const float*)d_in[13];
    float* out = (float*)d_out;

    float* ws = (float*)d_ws;
    float* xq     = ws;                    // 512*512
    float* xk     = ws + 262144;           // 512*512
    float* xc     = ws + 524288;           // 512*512
    float* E      = ws + 786432;           // 512*1536
    float* Cw     = ws + 1572864;          // 512*512
    float* u      = ws + 1835008;          // 512*512
    float* y      = ws + 2097152;          // 512*512
    float* outlin = ws + 2359296;          // 512*256

    k1_xp   <<<dim3(16, 8), 256, 0, stream>>>(x, W_in, xq, xk);
    k2_conv <<<dim3(8, 8),  256, 0, stream>>>(xk, conv_w, conv_b, xq, xc);
    k3_gemm <<<dim3(24, 8), 256, 0, stream>>>(xc, W_ssm, b_ssm, W_gate, b_gate, E);
    k3b_elem<<<256, 256, 0, stream>>>(E, xc, Cw, u);
    k4_scan <<<256, 256, 0, stream>>>(u, Cw, A, D, y);
    k5a_gemm<<<dim3(4, 8), 256, 0, stream>>>(y, W_out, outlin);
    k5b_ln  <<<512, 256, 0, stream>>>(outlin, x, z, ln_g, ln_b, out);
}

// Round 3
// 248.870 us; speedup vs baseline: 1.6574x; 1.4985x over previous
//
#include <hip/hip_runtime.h>
#include <math.h>

// Problem dims
#define NB    2
#define LSEQ  256
#define HDIM  256
#define IDIM  512
#define NROW  512      // NB*LSEQ
#define ESZ   1536     // effective fused ssm/gate output cols

// ---------------------------------------------------------------------------
// kW: Wc[k][o][h] = sum_i conv_w[o,i,k] * W_in[512+i][h]   (3x 512x256, K=512)
// grid (4,16,3): 64-wide h tiles, 32-wide o tiles, k in z.
// ---------------------------------------------------------------------------
__global__ __launch_bounds__(256) void kW_wc(const float* __restrict__ conv_w,
                                             const float* __restrict__ W_in,
                                             float* __restrict__ Wc) {
    __shared__ float As[32][36];   // [ii][o-local], 32 o
    __shared__ float Bs[32][68];   // [ii][h-local], 64 h
    const int h0 = blockIdx.x * 64;
    const int o0 = blockIdx.y * 32;
    const int kk = blockIdx.z;
    const int t = threadIdx.x;
    const int tx = t & 15, ty = t >> 4;
    float acc[2][4] = {};
    for (int i0 = 0; i0 < IDIM; i0 += 32) {
        for (int idx = t; idx < 1024; idx += 256) {
            int m = idx >> 5, ii = idx & 31;
            As[ii][m] = conv_w[((size_t)(o0 + m) * IDIM + i0 + ii) * 3 + kk];
        }
        for (int idx = t; idx < 2048; idx += 256) {
            int o = idx >> 5, ii = idx & 31;
            Bs[ii][o] = W_in[(size_t)(IDIM + i0 + ii) * HDIM + h0 + o];
        }
        __syncthreads();
        #pragma unroll
        for (int ii = 0; ii < 32; ++ii) {
            float2 av = *(const float2*)&As[ii][ty * 2];
            float4 bv = *(const float4*)&Bs[ii][tx * 4];
            const float* bp = (const float*)&bv;
            #pragma unroll
            for (int n = 0; n < 4; ++n) {
                acc[0][n] += av.x * bp[n];
                acc[1][n] += av.y * bp[n];
            }
        }
        __syncthreads();
    }
    #pragma unroll
    for (int mr = 0; mr < 2; ++mr) {
        int o = o0 + ty * 2 + mr;
        float4 v;
        v.x = acc[mr][0]; v.y = acc[mr][1]; v.z = acc[mr][2]; v.w = acc[mr][3];
        *(float4*)&Wc[((size_t)kk * IDIM + o) * HDIM + h0 + tx * 4] = v;
    }
}

// ---------------------------------------------------------------------------
// k_xc: xc[r,o] = gelu(x[r]·W_in[o]) + conv_b[o] + sum_k x[r+k-1]·Wc[k][o]
// (zero rows outside each batch's [0,256) range). Tiles 32r x 64o, grid(8,16).
// ---------------------------------------------------------------------------
__global__ __launch_bounds__(256) void k_xc(const float* __restrict__ x,
                                            const float* __restrict__ W_in,
                                            const float* __restrict__ Wc,
                                            const float* __restrict__ conv_b,
                                            float* __restrict__ xc) {
    __shared__ float Xs[32][36];     // [hh][m], m=0..33 <-> row r0-1+m
    __shared__ float Bq[32][68];     // W_in tile
    __shared__ float Bc[3][32][68];  // Wc tiles
    const int o0 = blockIdx.x * 64;
    const int r0 = blockIdx.y * 32;
    const int t = threadIdx.x;
    const int tx = t & 15, ty = t >> 4;
    const int lo = r0 & ~255, hi = lo + 256;   // batch row range
    float aq[2][4] = {};
    float ac[2][4] = {};
    for (int k0 = 0; k0 < HDIM; k0 += 32) {
        for (int idx = t; idx < 1088; idx += 256) {        // 34 x 32
            int m = idx >> 5, hh = idx & 31;
            int g = r0 - 1 + m;
            Xs[hh][m] = (g >= lo && g < hi) ? x[(size_t)g * HDIM + k0 + hh] : 0.0f;
        }
        for (int idx = t; idx < 2048; idx += 256) {        // 64 x 32
            int o = idx >> 5, hh = idx & 31;
            Bq[hh][o]    = W_in[(size_t)(o0 + o) * HDIM + k0 + hh];
            Bc[0][hh][o] = Wc[((size_t)0 * IDIM + o0 + o) * HDIM + k0 + hh];
            Bc[1][hh][o] = Wc[((size_t)1 * IDIM + o0 + o) * HDIM + k0 + hh];
            Bc[2][hh][o] = Wc[((size_t)2 * IDIM + o0 + o) * HDIM + k0 + hh];
        }
        __syncthreads();
        #pragma unroll
        for (int hh = 0; hh < 32; ++hh) {
            float xw[4];
            *(float2*)&xw[0] = *(const float2*)&Xs[hh][ty * 2];
            *(float2*)&xw[2] = *(const float2*)&Xs[hh][ty * 2 + 2];
            float4 bq = *(const float4*)&Bq[hh][tx * 4];
            float4 b0 = *(const float4*)&Bc[0][hh][tx * 4];
            float4 b1 = *(const float4*)&Bc[1][hh][tx * 4];
            float4 b2 = *(const float4*)&Bc[2][hh][tx * 4];
            const float* bqp = (const float*)&bq;
            const float* b0p = (const float*)&b0;
            const float* b1p = (const float*)&b1;
            const float* b2p = (const float*)&b2;
            #pragma unroll
            for (int mr = 0; mr < 2; ++mr) {
                #pragma unroll
                for (int n = 0; n < 4; ++n) {
                    aq[mr][n] += xw[mr + 1] * bqp[n];
                    ac[mr][n] += xw[mr] * b0p[n] + xw[mr + 1] * b1p[n] + xw[mr + 2] * b2p[n];
                }
            }
        }
        __syncthreads();
    }
    float4 cb = *(const float4*)&conv_b[o0 + tx * 4];
    const float* cbp = (const float*)&cb;
    #pragma unroll
    for (int mr = 0; mr < 2; ++mr) {
        int r = r0 + ty * 2 + mr;
        float4 v;
        float* vp = (float*)&v;
        #pragma unroll
        for (int n = 0; n < 4; ++n) {
            float q = aq[mr][n];
            float g = 0.5f * q * (1.0f + erff(q * 0.70710678118654752f));
            vp[n] = g + ac[mr][n] + cbp[n];
        }
        *(float4*)&xc[(size_t)r * IDIM + o0 + tx * 4] = v;
    }
}

// ---------------------------------------------------------------------------
// K3: E[r,j], j in [0,1536): fused {C_raw, D_w, gate_raw} GEMM over xc
// ---------------------------------------------------------------------------
__global__ __launch_bounds__(256) void k3_gemm(const float* __restrict__ xc,
                                               const float* __restrict__ W_ssm,
                                               const float* __restrict__ b_ssm,
                                               const float* __restrict__ W_gate,
                                               const float* __restrict__ b_gate,
                                               float* __restrict__ E) {
    __shared__ float As[32][68];
    __shared__ float Bs[32][68];
    const int r0 = blockIdx.y * 64;
    const int j0 = blockIdx.x * 64;
    const int t = threadIdx.x;
    const int tx = t & 15, ty = t >> 4;
    float acc[4][4] = {};
    for (int k0 = 0; k0 < IDIM; k0 += 32) {
        #pragma unroll
        for (int q = 0; q < 8; ++q) {
            int idx = t + q * 256;
            int m = idx >> 5, kk = idx & 31;
            int jj = j0 + m;
            const float* src = (jj < 1024) ? (W_ssm + (size_t)(512 + jj) * IDIM)
                                           : (W_gate + (size_t)(jj - 512) * IDIM);
            Bs[kk][m] = src[k0 + kk];
            As[kk][m] = xc[(size_t)(r0 + m) * IDIM + k0 + kk];
        }
        __syncthreads();
        #pragma unroll
        for (int kk = 0; kk < 32; ++kk) {
            float4 av = *(const float4*)&As[kk][ty * 4];
            float4 bv = *(const float4*)&Bs[kk][tx * 4];
            float a[4] = {av.x, av.y, av.z, av.w};
            float b[4] = {bv.x, bv.y, bv.z, bv.w};
            #pragma unroll
            for (int m = 0; m < 4; ++m)
                #pragma unroll
                for (int n = 0; n < 4; ++n) acc[m][n] += a[m] * b[n];
        }
        __syncthreads();
    }
    const bool iss = (j0 < 1024);
    #pragma unroll
    for (int m = 0; m < 4; ++m) {
        int r = r0 + ty * 4 + m;
        float4 bias = iss ? *(const float4*)&b_ssm[512 + j0 + tx * 4]
                          : *(const float4*)&b_gate[j0 - 512 + tx * 4];
        float4 v;
        v.x = acc[m][0] + bias.x;
        v.y = acc[m][1] + bias.y;
        v.z = acc[m][2] + bias.z;
        v.w = acc[m][3] + bias.w;
        *(float4*)&E[(size_t)r * ESZ + j0 + tx * 4] = v;
    }
}

// ---------------------------------------------------------------------------
// K3b: Cw[r,s] = sigmoid(E[r,1024+s]) * E[r,s];  u[r,i] = xc[r,i]*E[r,512+i]^2
// ---------------------------------------------------------------------------
__global__ __launch_bounds__(256) void k3b_elem(const float* __restrict__ E,
                                                const float* __restrict__ xc,
                                                float* __restrict__ Cw,
                                                float* __restrict__ u) {
    int idx4 = (blockIdx.x * 256 + threadIdx.x) * 4;  // < 512*512
    int r = idx4 >> 9, s = idx4 & 511;
    const float* Er = E + (size_t)r * ESZ;
    float4 craw = *(const float4*)&Er[s];
    float4 dw   = *(const float4*)&Er[512 + s];
    float4 graw = *(const float4*)&Er[1024 + s];
    float4 xcv  = *(const float4*)&xc[idx4];
    float4 cw, uv;
    cw.x = craw.x / (1.0f + expf(-graw.x));
    cw.y = craw.y / (1.0f + expf(-graw.y));
    cw.z = craw.z / (1.0f + expf(-graw.z));
    cw.w = craw.w / (1.0f + expf(-graw.w));
    uv.x = xcv.x * dw.x * dw.x;
    uv.y = xcv.y * dw.y * dw.y;
    uv.z = xcv.z * dw.z * dw.z;
    uv.w = xcv.w * dw.w * dw.w;
    *(float4*)&Cw[idx4] = cw;
    *(float4*)&u[idx4]  = uv;
}

// ---------------------------------------------------------------------------
// K4: scan + contraction over s. One wave per (b,i); lane owns 8 s-values.
// 4 l-steps per reduction batch -> 4 independent shfl chains overlap.
// ---------------------------------------------------------------------------
__global__ __launch_bounds__(256) void k4_scan(const float* __restrict__ u,
                                               const float* __restrict__ Cw,
                                               const float* __restrict__ A,
                                               const float* __restrict__ D,
                                               float* __restrict__ y) {
    const int wave = (blockIdx.x * 256 + threadIdx.x) >> 6;  // 0..1023
    const int lane = threadIdx.x & 63;
    const int b = wave >> 9, i = wave & 511;
    const int s8 = lane * 8;
    float a[8], h[8];
    #pragma unroll
    for (int j = 0; j < 8; ++j) {
        a[j] = A[(size_t)(s8 + j) * IDIM + i];
        h[j] = 0.0f;
    }
    const float Di = D[i];
    const float* ub = u + (size_t)b * LSEQ * IDIM;
    const float* cb = Cw + (size_t)b * LSEQ * IDIM;
    float* yb = y + (size_t)b * LSEQ * IDIM;
    for (int l0 = 0; l0 < LSEQ; l0 += 4) {
        float p[4];
        #pragma unroll
        for (int j = 0; j < 4; ++j) {
            const int l = l0 + j;
            const float4* up = (const float4*)(ub + l * IDIM + s8);
            const float4* cp = (const float4*)(cb + l * IDIM + s8);
            float4 u0 = up[0], u1 = up[1];
            float4 c0 = cp[0], c1 = cp[1];
            h[0] = h[0] * a[0] + u0.x; h[1] = h[1] * a[1] + u0.y;
            h[2] = h[2] * a[2] + u0.z; h[3] = h[3] * a[3] + u0.w;
            h[4] = h[4] * a[4] + u1.x; h[5] = h[5] * a[5] + u1.y;
            h[6] = h[6] * a[6] + u1.z; h[7] = h[7] * a[7] + u1.w;
            float p0 = c0.x * h[0] + c0.y * h[1] + c0.z * h[2] + c0.w * h[3];
            float p1 = c1.x * h[4] + c1.y * h[5] + c1.z * h[6] + c1.w * h[7];
            p[j] = p0 + p1;
        }
        #pragma unroll
        for (int off = 1; off < 64; off <<= 1) {
            #pragma unroll
            for (int j = 0; j < 4; ++j) p[j] += __shfl_xor(p[j], off, 64);
        }
        if (lane == 0) {
            #pragma unroll
            for (int j = 0; j < 4; ++j)
                yb[(l0 + j) * IDIM + i] = p[j] + ub[(l0 + j) * IDIM + i] * Di;
        }
    }
}

// ---------------------------------------------------------------------------
// K5a: outlin = y @ W_out^T  (512x512 @ 512x256). Tiles 32x32, grid(8,16).
// ---------------------------------------------------------------------------
__global__ __launch_bounds__(256) void k5a_gemm(const float* __restrict__ y,
                                                const float* __restrict__ W_out,
                                                float* __restrict__ outlin) {
    __shared__ float As[32][36];
    __shared__ float Bs[32][36];
    const int h0 = blockIdx.x * 32;
    const int r0 = blockIdx.y * 32;
    const int t = threadIdx.x;
    const int tx = t & 15, ty = t >> 4;
    float acc[2][2] = {};
    for (int k0 = 0; k0 < IDIM; k0 += 32) {
        #pragma unroll
        for (int q = 0; q < 4; ++q) {
            int idx = t + q * 256;
            int m = idx >> 5, kk = idx & 31;
            As[kk][m] = y[(size_t)(r0 + m) * IDIM + k0 + kk];
            Bs[kk][m] = W_out[(size_t)(h0 + m) * IDIM + k0 + kk];
        }
        __syncthreads();
        #pragma unroll
        for (int kk = 0; kk < 32; ++kk) {
            float2 av = *(const float2*)&As[kk][ty * 2];
            float2 bv = *(const float2*)&Bs[kk][tx * 2];
            acc[0][0] += av.x * bv.x;
            acc[0][1] += av.x * bv.y;
            acc[1][0] += av.y * bv.x;
            acc[1][1] += av.y * bv.y;
        }
        __syncthreads();
    }
    #pragma unroll
    for (int mr = 0; mr < 2; ++mr) {
        int r = r0 + ty * 2 + mr;
        float2 v;
        v.x = acc[mr][0]; v.y = acc[mr][1];
        *(float2*)&outlin[(size_t)r * HDIM + h0 + tx * 2] = v;
    }
}

// ---------------------------------------------------------------------------
// K5b: LayerNorm over H=256 + z scale + residual. One block per row.
// ---------------------------------------------------------------------------
__global__ __launch_bounds__(256) void k5b_ln(const float* __restrict__ outlin,
                                              const float* __restrict__ x,
                                              const float* __restrict__ z,
                                              const float* __restrict__ ln_g,
                                              const float* __restrict__ ln_b,
                                              float* __restrict__ out) {
    const int r = blockIdx.x;
    const int t = threadIdx.x;
    float v = outlin[(size_t)r * HDIM + t];
    float s1 = v, s2 = v * v;
    #pragma unroll
    for (int off = 1; off < 64; off <<= 1) {
        s1 += __shfl_xor(s1, off, 64);
        s2 += __shfl_xor(s2, off, 64);
    }
    __shared__ float r1[4], r2[4];
    const int w = t >> 6, lane = t & 63;
    if (lane == 0) { r1[w] = s1; r2[w] = s2; }
    __syncthreads();
    float t1 = r1[0] + r1[1] + r1[2] + r1[3];
    float t2 = r2[0] + r2[1] + r2[2] + r2[3];
    float mu = t1 * (1.0f / 256.0f);
    float var = t2 * (1.0f / 256.0f) - mu * mu;
    float inv = rsqrtf(var + 1e-5f);
    float o = (v - mu) * inv * ln_g[t] + ln_b[t];
    out[(size_t)r * HDIM + t] = o * z[0] + x[(size_t)r * HDIM + t];
}

// ---------------------------------------------------------------------------
extern "C" void kernel_launch(void* const* d_in, const int* in_sizes, int n_in,
                              void* d_out, int out_size, void* d_ws, size_t ws_size,
                              hipStream_t stream) {
    const float* x      = (const float*)d_in[0];
    const float* W_in   = (const float*)d_in[1];
    const float* conv_w = (const float*)d_in[2];
    const float* conv_b = (const float*)d_in[3];
    const float* W_ssm  = (const float*)d_in[4];
    const float* b_ssm  = (const float*)d_in[5];
    const float* W_gate = (const float*)d_in[6];
    const float* b_gate = (const float*)d_in[7];
    const float* A      = (const float*)d_in[8];
    const float* D      = (const float*)d_in[9];
    const float* W_out  = (const float*)d_in[10];
    const float* z      = (const float*)d_in[11];
    const float* ln_g   = (const float*)d_in[12];
    const float* ln_b   = (const float*)d_in[13];
    float* out = (float*)d_out;

    float* ws = (float*)d_ws;
    float* Wc     = ws;                    // 3*512*256 = 393216
    float* xc     = ws + 393216;           // 512*512
    float* E      = ws + 655360;           // 512*1536
    float* Cw     = ws + 1441792;          // 512*512
    float* u      = ws + 1703936;          // 512*512
    float* y      = ws + 1966080;          // 512*512
    float* outlin = ws + 2228224;          // 512*256

    kW_wc   <<<dim3(4, 16, 3), 256, 0, stream>>>(conv_w, W_in, Wc);
    k_xc    <<<dim3(8, 16), 256, 0, stream>>>(x, W_in, Wc, conv_b, xc);
    k3_gemm <<<dim3(24, 8), 256, 0, stream>>>(xc, W_ssm, b_ssm, W_gate, b_gate, E);
    k3b_elem<<<256, 256, 0, stream>>>(E, xc, Cw, u);
    k4_scan <<<256, 256, 0, stream>>>(u, Cw, A, D, y);
    k5a_gemm<<<dim3(8, 16), 256, 0, stream>>>(y, W_out, outlin);
    k5b_ln  <<<512, 256, 0, stream>>>(outlin, x, z, ln_g, ln_b, out);
}

// Round 4
// 235.807 us; speedup vs baseline: 1.7492x; 1.0554x over previous
//
#include <hip/hip_runtime.h>
#include <math.h>

// Problem dims
#define NB    2
#define LSEQ  256
#define HDIM  256
#define IDIM  512
#define NROW  512      // NB*LSEQ
#define ESZ   1536     // effective fused ssm/gate output cols
#define NC    4        // scan chunks
#define TCH   64       // chunk length (NC*TCH == LSEQ)

// ---------------------------------------------------------------------------
// kW: Wc[k][o][h] = sum_i conv_w[o,i,k] * W_in[512+i][h]   (3x 512x256, K=512)
// ---------------------------------------------------------------------------
__global__ __launch_bounds__(256) void kW_wc(const float* __restrict__ conv_w,
                                             const float* __restrict__ W_in,
                                             float* __restrict__ Wc) {
    __shared__ float As[32][36];   // [ii][o-local], 32 o
    __shared__ float Bs[32][68];   // [ii][h-local], 64 h
    const int h0 = blockIdx.x * 64;
    const int o0 = blockIdx.y * 32;
    const int kk = blockIdx.z;
    const int t = threadIdx.x;
    const int tx = t & 15, ty = t >> 4;
    float acc[2][4] = {};
    for (int i0 = 0; i0 < IDIM; i0 += 32) {
        for (int idx = t; idx < 1024; idx += 256) {
            int m = idx >> 5, ii = idx & 31;
            As[ii][m] = conv_w[((size_t)(o0 + m) * IDIM + i0 + ii) * 3 + kk];
        }
        for (int idx = t; idx < 2048; idx += 256) {
            int o = idx >> 5, ii = idx & 31;
            Bs[ii][o] = W_in[(size_t)(IDIM + i0 + ii) * HDIM + h0 + o];
        }
        __syncthreads();
        #pragma unroll
        for (int ii = 0; ii < 32; ++ii) {
            float2 av = *(const float2*)&As[ii][ty * 2];
            float4 bv = *(const float4*)&Bs[ii][tx * 4];
            const float* bp = (const float*)&bv;
            #pragma unroll
            for (int n = 0; n < 4; ++n) {
                acc[0][n] += av.x * bp[n];
                acc[1][n] += av.y * bp[n];
            }
        }
        __syncthreads();
    }
    #pragma unroll
    for (int mr = 0; mr < 2; ++mr) {
        int o = o0 + ty * 2 + mr;
        float4 v;
        v.x = acc[mr][0]; v.y = acc[mr][1]; v.z = acc[mr][2]; v.w = acc[mr][3];
        *(float4*)&Wc[((size_t)kk * IDIM + o) * HDIM + h0 + tx * 4] = v;
    }
}

// ---------------------------------------------------------------------------
// k_xc: xc[r,o] = gelu(x[r]·W_in[o]) + conv_b[o] + sum_k x[r+k-1]·Wc[k][o]
// ---------------------------------------------------------------------------
__global__ __launch_bounds__(256) void k_xc(const float* __restrict__ x,
                                            const float* __restrict__ W_in,
                                            const float* __restrict__ Wc,
                                            const float* __restrict__ conv_b,
                                            float* __restrict__ xc) {
    __shared__ float Xs[32][36];     // [hh][m], m=0..33 <-> row r0-1+m
    __shared__ float Bq[32][68];     // W_in tile
    __shared__ float Bc[3][32][68];  // Wc tiles
    const int o0 = blockIdx.x * 64;
    const int r0 = blockIdx.y * 32;
    const int t = threadIdx.x;
    const int tx = t & 15, ty = t >> 4;
    const int lo = r0 & ~255, hi = lo + 256;   // batch row range
    float aq[2][4] = {};
    float ac[2][4] = {};
    for (int k0 = 0; k0 < HDIM; k0 += 32) {
        for (int idx = t; idx < 1088; idx += 256) {        // 34 x 32
            int m = idx >> 5, hh = idx & 31;
            int g = r0 - 1 + m;
            Xs[hh][m] = (g >= lo && g < hi) ? x[(size_t)g * HDIM + k0 + hh] : 0.0f;
        }
        for (int idx = t; idx < 2048; idx += 256) {        // 64 x 32
            int o = idx >> 5, hh = idx & 31;
            Bq[hh][o]    = W_in[(size_t)(o0 + o) * HDIM + k0 + hh];
            Bc[0][hh][o] = Wc[((size_t)0 * IDIM + o0 + o) * HDIM + k0 + hh];
            Bc[1][hh][o] = Wc[((size_t)1 * IDIM + o0 + o) * HDIM + k0 + hh];
            Bc[2][hh][o] = Wc[((size_t)2 * IDIM + o0 + o) * HDIM + k0 + hh];
        }
        __syncthreads();
        #pragma unroll
        for (int hh = 0; hh < 32; ++hh) {
            float xw[4];
            *(float2*)&xw[0] = *(const float2*)&Xs[hh][ty * 2];
            *(float2*)&xw[2] = *(const float2*)&Xs[hh][ty * 2 + 2];
            float4 bq = *(const float4*)&Bq[hh][tx * 4];
            float4 b0 = *(const float4*)&Bc[0][hh][tx * 4];
            float4 b1 = *(const float4*)&Bc[1][hh][tx * 4];
            float4 b2 = *(const float4*)&Bc[2][hh][tx * 4];
            const float* bqp = (const float*)&bq;
            const float* b0p = (const float*)&b0;
            const float* b1p = (const float*)&b1;
            const float* b2p = (const float*)&b2;
            #pragma unroll
            for (int mr = 0; mr < 2; ++mr) {
                #pragma unroll
                for (int n = 0; n < 4; ++n) {
                    aq[mr][n] += xw[mr + 1] * bqp[n];
                    ac[mr][n] += xw[mr] * b0p[n] + xw[mr + 1] * b1p[n] + xw[mr + 2] * b2p[n];
                }
            }
        }
        __syncthreads();
    }
    float4 cb = *(const float4*)&conv_b[o0 + tx * 4];
    const float* cbp = (const float*)&cb;
    #pragma unroll
    for (int mr = 0; mr < 2; ++mr) {
        int r = r0 + ty * 2 + mr;
        float4 v;
        float* vp = (float*)&v;
        #pragma unroll
        for (int n = 0; n < 4; ++n) {
            float q = aq[mr][n];
            float g = 0.5f * q * (1.0f + erff(q * 0.70710678118654752f));
            vp[n] = g + ac[mr][n] + cbp[n];
        }
        *(float4*)&xc[(size_t)r * IDIM + o0 + tx * 4] = v;
    }
}

// ---------------------------------------------------------------------------
// K3: E[r,j], j in [0,1536): fused {C_raw, D_w, gate_raw} GEMM over xc
// ---------------------------------------------------------------------------
__global__ __launch_bounds__(256) void k3_gemm(const float* __restrict__ xc,
                                               const float* __restrict__ W_ssm,
                                               const float* __restrict__ b_ssm,
                                               const float* __restrict__ W_gate,
                                               const float* __restrict__ b_gate,
                                               float* __restrict__ E) {
    __shared__ float As[32][68];
    __shared__ float Bs[32][68];
    const int r0 = blockIdx.y * 64;
    const int j0 = blockIdx.x * 64;
    const int t = threadIdx.x;
    const int tx = t & 15, ty = t >> 4;
    float acc[4][4] = {};
    for (int k0 = 0; k0 < IDIM; k0 += 32) {
        #pragma unroll
        for (int q = 0; q < 8; ++q) {
            int idx = t + q * 256;
            int m = idx >> 5, kk = idx & 31;
            int jj = j0 + m;
            const float* src = (jj < 1024) ? (W_ssm + (size_t)(512 + jj) * IDIM)
                                           : (W_gate + (size_t)(jj - 512) * IDIM);
            Bs[kk][m] = src[k0 + kk];
            As[kk][m] = xc[(size_t)(r0 + m) * IDIM + k0 + kk];
        }
        __syncthreads();
        #pragma unroll
        for (int kk = 0; kk < 32; ++kk) {
            float4 av = *(const float4*)&As[kk][ty * 4];
            float4 bv = *(const float4*)&Bs[kk][tx * 4];
            float a[4] = {av.x, av.y, av.z, av.w};
            float b[4] = {bv.x, bv.y, bv.z, bv.w};
            #pragma unroll
            for (int m = 0; m < 4; ++m)
                #pragma unroll
                for (int n = 0; n < 4; ++n) acc[m][n] += a[m] * b[n];
        }
        __syncthreads();
    }
    const bool iss = (j0 < 1024);
    #pragma unroll
    for (int m = 0; m < 4; ++m) {
        int r = r0 + ty * 4 + m;
        float4 bias = iss ? *(const float4*)&b_ssm[512 + j0 + tx * 4]
                          : *(const float4*)&b_gate[j0 - 512 + tx * 4];
        float4 v;
        v.x = acc[m][0] + bias.x;
        v.y = acc[m][1] + bias.y;
        v.z = acc[m][2] + bias.z;
        v.w = acc[m][3] + bias.w;
        *(float4*)&E[(size_t)r * ESZ + j0 + tx * 4] = v;
    }
}

// ---------------------------------------------------------------------------
// K3b: Cw[r,s] = sigmoid(E[r,1024+s]) * E[r,s];  u[r,i] = xc[r,i]*E[r,512+i]^2
// ---------------------------------------------------------------------------
__global__ __launch_bounds__(256) void k3b_elem(const float* __restrict__ E,
                                                const float* __restrict__ xc,
                                                float* __restrict__ Cw,
                                                float* __restrict__ u) {
    int idx4 = (blockIdx.x * 256 + threadIdx.x) * 4;  // < 512*512
    int r = idx4 >> 9, s = idx4 & 511;
    const float* Er = E + (size_t)r * ESZ;
    float4 craw = *(const float4*)&Er[s];
    float4 dw   = *(const float4*)&Er[512 + s];
    float4 graw = *(const float4*)&Er[1024 + s];
    float4 xcv  = *(const float4*)&xc[idx4];
    float4 cw, uv;
    cw.x = craw.x / (1.0f + expf(-graw.x));
    cw.y = craw.y / (1.0f + expf(-graw.y));
    cw.z = craw.z / (1.0f + expf(-graw.z));
    cw.w = craw.w / (1.0f + expf(-graw.w));
    uv.x = xcv.x * dw.x * dw.x;
    uv.y = xcv.y * dw.y * dw.y;
    uv.z = xcv.z * dw.z * dw.z;
    uv.w = xcv.w * dw.w * dw.w;
    *(float4*)&Cw[idx4] = cw;
    *(float4*)&u[idx4]  = uv;
}

// ---------------------------------------------------------------------------
// K4a: chunk-local scan from h=0; write chunk-final carry C_loc[b][c][i][s].
// Wave per (b,c,i); lane owns 8 s-values.
// ---------------------------------------------------------------------------
__global__ __launch_bounds__(256) void k4a_pass1(const float* __restrict__ u,
                                                 const float* __restrict__ A,
                                                 float* __restrict__ C_loc) {
    const int wave = (blockIdx.x * 256 + threadIdx.x) >> 6;  // 0..4095
    const int lane = threadIdx.x & 63;
    const int i = wave & 511;
    const int c = (wave >> 9) & (NC - 1);
    const int b = wave >> 11;
    const int s8 = lane * 8;
    float a[8], h[8];
    #pragma unroll
    for (int j = 0; j < 8; ++j) {
        a[j] = A[(size_t)(s8 + j) * IDIM + i];
        h[j] = 0.0f;
    }
    const float* ub = u + ((size_t)b * LSEQ + c * TCH) * IDIM;
    for (int l = 0; l < TCH; ++l) {
        float4 u0 = *(const float4*)(ub + l * IDIM + s8);
        float4 u1 = *(const float4*)(ub + l * IDIM + s8 + 4);
        h[0] = h[0] * a[0] + u0.x; h[1] = h[1] * a[1] + u0.y;
        h[2] = h[2] * a[2] + u0.z; h[3] = h[3] * a[3] + u0.w;
        h[4] = h[4] * a[4] + u1.x; h[5] = h[5] * a[5] + u1.y;
        h[6] = h[6] * a[6] + u1.z; h[7] = h[7] * a[7] + u1.w;
    }
    float* cp = C_loc + (((size_t)b * NC + c) * IDIM + i) * IDIM + s8;
    float4 v0, v1;
    v0.x = h[0]; v0.y = h[1]; v0.z = h[2]; v0.w = h[3];
    v1.x = h[4]; v1.y = h[5]; v1.z = h[6]; v1.w = h[7];
    *(float4*)cp = v0;
    *(float4*)(cp + 4) = v1;
}

// ---------------------------------------------------------------------------
// K4b: sequential combine over chunks: H[b][c] = state entering chunk c.
// h_{c} = h_{c-1} * A^TCH + C_loc[c-1], h_0 = 0. Thread per (b,i,s4).
// ---------------------------------------------------------------------------
__global__ __launch_bounds__(256) void k4b_combine(const float* __restrict__ A,
                                                   const float* __restrict__ C_loc,
                                                   float* __restrict__ H) {
    int idx = blockIdx.x * 256 + threadIdx.x;   // < 2*512*128
    int s4 = (idx & 127) * 4;
    int i  = (idx >> 7) & 511;
    int b  = idx >> 16;
    float da[4], h4[4] = {0.0f, 0.0f, 0.0f, 0.0f};
    #pragma unroll
    for (int j = 0; j < 4; ++j) {
        float aa = A[(size_t)(s4 + j) * IDIM + i];
        aa = aa * aa;   // ^2
        aa = aa * aa;   // ^4
        aa = aa * aa;   // ^8
        aa = aa * aa;   // ^16
        aa = aa * aa;   // ^32
        aa = aa * aa;   // ^64 == TCH
        da[j] = aa;
    }
    for (int c = 0; c < NC; ++c) {
        size_t base = (((size_t)b * NC + c) * IDIM + i) * IDIM + s4;
        float4 hv;
        hv.x = h4[0]; hv.y = h4[1]; hv.z = h4[2]; hv.w = h4[3];
        *(float4*)&H[base] = hv;
        float4 cl = *(const float4*)&C_loc[base];
        h4[0] = h4[0] * da[0] + cl.x;
        h4[1] = h4[1] * da[1] + cl.y;
        h4[2] = h4[2] * da[2] + cl.z;
        h4[3] = h4[3] * da[3] + cl.w;
    }
}

// ---------------------------------------------------------------------------
// K4c: seeded chunk scan + contraction. Wave per (b,c,i); lane owns 8 s.
// ---------------------------------------------------------------------------
__global__ __launch_bounds__(256) void k4c_pass2(const float* __restrict__ u,
                                                 const float* __restrict__ Cw,
                                                 const float* __restrict__ A,
                                                 const float* __restrict__ D,
                                                 const float* __restrict__ H,
                                                 float* __restrict__ y) {
    const int wave = (blockIdx.x * 256 + threadIdx.x) >> 6;  // 0..4095
    const int lane = threadIdx.x & 63;
    const int i = wave & 511;
    const int c = (wave >> 9) & (NC - 1);
    const int b = wave >> 11;
    const int s8 = lane * 8;
    float a[8], h[8];
    #pragma unroll
    for (int j = 0; j < 8; ++j) a[j] = A[(size_t)(s8 + j) * IDIM + i];
    const float* hp = H + (((size_t)b * NC + c) * IDIM + i) * IDIM + s8;
    float4 h0v = *(const float4*)hp;
    float4 h1v = *(const float4*)(hp + 4);
    h[0] = h0v.x; h[1] = h0v.y; h[2] = h0v.z; h[3] = h0v.w;
    h[4] = h1v.x; h[5] = h1v.y; h[6] = h1v.z; h[7] = h1v.w;
    const float Di = D[i];
    const float* ub = u + (size_t)b * LSEQ * IDIM;
    const float* cb = Cw + (size_t)b * LSEQ * IDIM;
    float* yb = y + (size_t)b * LSEQ * IDIM;
    for (int l0 = c * TCH; l0 < c * TCH + TCH; l0 += 4) {
        float p[4];
        #pragma unroll
        for (int j = 0; j < 4; ++j) {
            const int l = l0 + j;
            const float4* up = (const float4*)(ub + l * IDIM + s8);
            const float4* cp = (const float4*)(cb + l * IDIM + s8);
            float4 u0 = up[0], u1 = up[1];
            float4 c0 = cp[0], c1 = cp[1];
            h[0] = h[0] * a[0] + u0.x; h[1] = h[1] * a[1] + u0.y;
            h[2] = h[2] * a[2] + u0.z; h[3] = h[3] * a[3] + u0.w;
            h[4] = h[4] * a[4] + u1.x; h[5] = h[5] * a[5] + u1.y;
            h[6] = h[6] * a[6] + u1.z; h[7] = h[7] * a[7] + u1.w;
            float p0 = c0.x * h[0] + c0.y * h[1] + c0.z * h[2] + c0.w * h[3];
            float p1 = c1.x * h[4] + c1.y * h[5] + c1.z * h[6] + c1.w * h[7];
            p[j] = p0 + p1;
        }
        #pragma unroll
        for (int off = 1; off < 64; off <<= 1) {
            #pragma unroll
            for (int j = 0; j < 4; ++j) p[j] += __shfl_xor(p[j], off, 64);
        }
        if (lane == 0) {
            #pragma unroll
            for (int j = 0; j < 4; ++j)
                yb[(l0 + j) * IDIM + i] = p[j] + ub[(l0 + j) * IDIM + i] * Di;
        }
    }
}

// ---------------------------------------------------------------------------
// K5a: outlin = y @ W_out^T  (512x512 @ 512x256). Tiles 32x32, grid(8,16).
// ---------------------------------------------------------------------------
__global__ __launch_bounds__(256) void k5a_gemm(const float* __restrict__ y,
                                                const float* __restrict__ W_out,
                                                float* __restrict__ outlin) {
    __shared__ float As[32][36];
    __shared__ float Bs[32][36];
    const int h0 = blockIdx.x * 32;
    const int r0 = blockIdx.y * 32;
    const int t = threadIdx.x;
    const int tx = t & 15, ty = t >> 4;
    float acc[2][2] = {};
    for (int k0 = 0; k0 < IDIM; k0 += 32) {
        #pragma unroll
        for (int q = 0; q < 4; ++q) {
            int idx = t + q * 256;
            int m = idx >> 5, kk = idx & 31;
            As[kk][m] = y[(size_t)(r0 + m) * IDIM + k0 + kk];
            Bs[kk][m] = W_out[(size_t)(h0 + m) * IDIM + k0 + kk];
        }
        __syncthreads();
        #pragma unroll
        for (int kk = 0; kk < 32; ++kk) {
            float2 av = *(const float2*)&As[kk][ty * 2];
            float2 bv = *(const float2*)&Bs[kk][tx * 2];
            acc[0][0] += av.x * bv.x;
            acc[0][1] += av.x * bv.y;
            acc[1][0] += av.y * bv.x;
            acc[1][1] += av.y * bv.y;
        }
        __syncthreads();
    }
    #pragma unroll
    for (int mr = 0; mr < 2; ++mr) {
        int r = r0 + ty * 2 + mr;
        float2 v;
        v.x = acc[mr][0]; v.y = acc[mr][1];
        *(float2*)&outlin[(size_t)r * HDIM + h0 + tx * 2] = v;
    }
}

// ---------------------------------------------------------------------------
// K5b: LayerNorm over H=256 + z scale + residual. One block per row.
// ---------------------------------------------------------------------------
__global__ __launch_bounds__(256) void k5b_ln(const float* __restrict__ outlin,
                                              const float* __restrict__ x,
                                              const float* __restrict__ z,
                                              const float* __restrict__ ln_g,
                                              const float* __restrict__ ln_b,
                                              float* __restrict__ out) {
    const int r = blockIdx.x;
    const int t = threadIdx.x;
    float v = outlin[(size_t)r * HDIM + t];
    float s1 = v, s2 = v * v;
    #pragma unroll
    for (int off = 1; off < 64; off <<= 1) {
        s1 += __shfl_xor(s1, off, 64);
        s2 += __shfl_xor(s2, off, 64);
    }
    __shared__ float r1[4], r2[4];
    const int w = t >> 6, lane = t & 63;
    if (lane == 0) { r1[w] = s1; r2[w] = s2; }
    __syncthreads();
    float t1 = r1[0] + r1[1] + r1[2] + r1[3];
    float t2 = r2[0] + r2[1] + r2[2] + r2[3];
    float mu = t1 * (1.0f / 256.0f);
    float var = t2 * (1.0f / 256.0f) - mu * mu;
    float inv = rsqrtf(var + 1e-5f);
    float o = (v - mu) * inv * ln_g[t] + ln_b[t];
    out[(size_t)r * HDIM + t] = o * z[0] + x[(size_t)r * HDIM + t];
}

// ---------------------------------------------------------------------------
extern "C" void kernel_launch(void* const* d_in, const int* in_sizes, int n_in,
                              void* d_out, int out_size, void* d_ws, size_t ws_size,
                              hipStream_t stream) {
    const float* x      = (const float*)d_in[0];
    const float* W_in   = (const float*)d_in[1];
    const float* conv_w = (const float*)d_in[2];
    const float* conv_b = (const float*)d_in[3];
    const float* W_ssm  = (const float*)d_in[4];
    const float* b_ssm  = (const float*)d_in[5];
    const float* W_gate = (const float*)d_in[6];
    const float* b_gate = (const float*)d_in[7];
    const float* A      = (const float*)d_in[8];
    const float* D      = (const float*)d_in[9];
    const float* W_out  = (const float*)d_in[10];
    const float* z      = (const float*)d_in[11];
    const float* ln_g   = (const float*)d_in[12];
    const float* ln_b   = (const float*)d_in[13];
    float* out = (float*)d_out;

    float* ws = (float*)d_ws;
    float* Wc     = ws;                    // 3*512*256 = 393216
    float* xc     = ws + 393216;           // 512*512
    float* E      = ws + 655360;           // 512*1536
    float* Cw     = ws + 1441792;          // 512*512
    float* u      = ws + 1703936;          // 512*512
    float* y      = ws + 1966080;          // 512*512
    float* outlin = ws + 2228224;          // 512*256
    float* C_loc  = ws + 2359296;          // 2*4*512*512 = 2097152
    float* Hbuf   = ws + 4456448;          // 2097152  (total 6553600 floats = 26.2 MB)

    kW_wc      <<<dim3(4, 16, 3), 256, 0, stream>>>(conv_w, W_in, Wc);
    k_xc       <<<dim3(8, 16), 256, 0, stream>>>(x, W_in, Wc, conv_b, xc);
    k3_gemm    <<<dim3(24, 8), 256, 0, stream>>>(xc, W_ssm, b_ssm, W_gate, b_gate, E);
    k3b_elem   <<<256, 256, 0, stream>>>(E, xc, Cw, u);
    k4a_pass1  <<<1024, 256, 0, stream>>>(u, A, C_loc);
    k4b_combine<<<512, 256, 0, stream>>>(A, C_loc, Hbuf);
    k4c_pass2  <<<1024, 256, 0, stream>>>(u, Cw, A, D, Hbuf, y);
    k5a_gemm   <<<dim3(8, 16), 256, 0, stream>>>(y, W_out, outlin);
    k5b_ln     <<<512, 256, 0, stream>>>(outlin, x, z, ln_g, ln_b, out);
}

// Round 5
// 129.868 us; speedup vs baseline: 3.1761x; 1.8157x over previous
//
#include <hip/hip_runtime.h>
#include <math.h>

// Problem dims
#define NB    2
#define LSEQ  256
#define HDIM  256
#define IDIM  512
#define NROW  512      // NB*LSEQ
#define ESZ   1536     // effective fused ssm/gate output cols
#define NC    4        // scan chunks
#define TCH   64       // chunk length (NC*TCH == LSEQ)

typedef __attribute__((ext_vector_type(8))) short bf16x8;
typedef __attribute__((ext_vector_type(4))) float f32x4;

__device__ inline unsigned short f2b(float f) {
    unsigned u = __float_as_uint(f);
    return (unsigned short)((u + 0x7FFFu + ((u >> 16) & 1u)) >> 16);
}

// ---------------------------------------------------------------------------
// kcvt: convert x, W_in, conv_w (3 transposed planes), fused Wsg, bsg, W_out
// to bf16 staging buffers. Memory-bound, grid-stride.
// ---------------------------------------------------------------------------
__global__ __launch_bounds__(256) void kcvt(const float* __restrict__ x,
                                            const float* __restrict__ W_in,
                                            const float* __restrict__ conv_w,
                                            const float* __restrict__ W_ssm,
                                            const float* __restrict__ W_gate,
                                            const float* __restrict__ b_ssm,
                                            const float* __restrict__ b_gate,
                                            const float* __restrict__ W_out,
                                            unsigned short* __restrict__ xb,
                                            unsigned short* __restrict__ Wb,
                                            unsigned short* __restrict__ cwb,
                                            unsigned short* __restrict__ Wsgb,
                                            float* __restrict__ bsg,
                                            unsigned short* __restrict__ W_outb) {
    const int stride = gridDim.x * 256;
    const int t0 = blockIdx.x * 256 + threadIdx.x;
    for (int i = t0; i < 131072; i += stride) xb[i] = f2b(x[i]);
    for (int i = t0; i < 262144; i += stride) Wb[i] = f2b(W_in[i]);
    // cwb[k][o][i] = conv_w[o][i][k]; thread handles one (o,i), 3 planes
    for (int d = t0; d < 262144; d += stride) {
        const float* s = conv_w + (size_t)d * 3;
        cwb[d]          = f2b(s[0]);
        cwb[262144 + d] = f2b(s[1]);
        cwb[524288 + d] = f2b(s[2]);
    }
    // Wsgb rows: 0..1023 = W_ssm[512..1535]; 1024..1535 = W_gate[512..1023]
    for (int d = t0; d < 786432; d += stride) {
        int j = d >> 9, i = d & 511;
        float v = (j < 1024) ? W_ssm[(size_t)(512 + j) * 512 + i]
                             : W_gate[(size_t)(j - 512) * 512 + i];
        Wsgb[d] = f2b(v);
    }
    for (int j = t0; j < 1536; j += stride)
        bsg[j] = (j < 1024) ? b_ssm[512 + j] : b_gate[j - 512];
    for (int i = t0; i < 131072; i += stride) W_outb[i] = f2b(W_out[i]);
}

// ---------------------------------------------------------------------------
// k1: xp = x @ W_in^T (512x1024, K=256). Wave per 16x16 tile, no LDS.
// o<512 -> gelu -> xq_g (fp32); o>=512 -> xkb (bf16).
// ---------------------------------------------------------------------------
__global__ __launch_bounds__(256) void k1_mfma(const unsigned short* __restrict__ xb,
                                               const unsigned short* __restrict__ Wb,
                                               float* __restrict__ xq_g,
                                               unsigned short* __restrict__ xkb) {
    const int t = threadIdx.x;
    const int w = blockIdx.x * 4 + (t >> 6);   // 0..2047
    const int lane = t & 63;
    const int mt = w >> 6, nt = w & 63;
    const int r0 = mt * 16, n0 = nt * 16;
    const int fr = lane & 15, fk = (lane >> 4) * 8;
    const unsigned short* ap = xb + (size_t)(r0 + fr) * HDIM + fk;
    const unsigned short* bp = Wb + (size_t)(n0 + fr) * HDIM + fk;
    f32x4 acc = {0.f, 0.f, 0.f, 0.f};
    #pragma unroll
    for (int k0 = 0; k0 < HDIM; k0 += 32) {
        bf16x8 av = *(const bf16x8*)(ap + k0);
        bf16x8 bv = *(const bf16x8*)(bp + k0);
        acc = __builtin_amdgcn_mfma_f32_16x16x32_bf16(av, bv, acc, 0, 0, 0);
    }
    const int orow = (lane >> 4) * 4;
    const int oc = n0 + fr;
    if (oc < IDIM) {
        #pragma unroll
        for (int j = 0; j < 4; ++j) {
            float v = acc[j];
            xq_g[(size_t)(r0 + orow + j) * IDIM + oc] =
                0.5f * v * (1.0f + erff(v * 0.70710678118654752f));
        }
    } else {
        #pragma unroll
        for (int j = 0; j < 4; ++j)
            xkb[(size_t)(r0 + orow + j) * IDIM + (oc - IDIM)] = f2b(acc[j]);
    }
}

// ---------------------------------------------------------------------------
// kxc: xc[r,o] = gelu_q[r,o] + conv_b[o] + sum_k xk[r+k-1,:]·cwb[k][o,:]
// 3 shifted bf16 GEMMs, wave per 16x16 tile. Writes fp32 + bf16 copies.
// ---------------------------------------------------------------------------
__global__ __launch_bounds__(256) void kxc_mfma(const unsigned short* __restrict__ xkb,
                                                const unsigned short* __restrict__ cwb,
                                                const float* __restrict__ xq_g,
                                                const float* __restrict__ conv_b,
                                                float* __restrict__ xc,
                                                unsigned short* __restrict__ xcb) {
    const int t = threadIdx.x;
    const int w = blockIdx.x * 4 + (t >> 6);   // 0..1023
    const int lane = t & 63;
    const int mt = w >> 5, nt = w & 31;
    const int r0 = mt * 16, o0 = nt * 16;
    const int fr = lane & 15, fk = (lane >> 4) * 8;
    const int g = r0 + fr;
    const int lo = r0 & ~255, hi = lo + 256;
    const bool okm = (g - 1 >= lo), okp = (g + 1 < hi);
    const unsigned short* am = xkb + (size_t)(g - 1) * IDIM + fk;
    const unsigned short* a0 = xkb + (size_t)g * IDIM + fk;
    const unsigned short* ap = xkb + (size_t)(g + 1) * IDIM + fk;
    const unsigned short* b0 = cwb + (size_t)(o0 + fr) * IDIM + fk;
    const unsigned short* b1 = b0 + 262144;
    const unsigned short* b2 = b0 + 524288;
    const bf16x8 zz = {0, 0, 0, 0, 0, 0, 0, 0};
    f32x4 acc = {0.f, 0.f, 0.f, 0.f};
    #pragma unroll
    for (int k0 = 0; k0 < IDIM; k0 += 32) {
        bf16x8 avm = okm ? *(const bf16x8*)(am + k0) : zz;
        bf16x8 av0 = *(const bf16x8*)(a0 + k0);
        bf16x8 avp = okp ? *(const bf16x8*)(ap + k0) : zz;
        bf16x8 bv0 = *(const bf16x8*)(b0 + k0);
        bf16x8 bv1 = *(const bf16x8*)(b1 + k0);
        bf16x8 bv2 = *(const bf16x8*)(b2 + k0);
        acc = __builtin_amdgcn_mfma_f32_16x16x32_bf16(avm, bv0, acc, 0, 0, 0);
        acc = __builtin_amdgcn_mfma_f32_16x16x32_bf16(av0, bv1, acc, 0, 0, 0);
        acc = __builtin_amdgcn_mfma_f32_16x16x32_bf16(avp, bv2, acc, 0, 0, 0);
    }
    const int orow = (lane >> 4) * 4;
    const int oc = o0 + fr;
    const float cb = conv_b[oc];
    #pragma unroll
    for (int j = 0; j < 4; ++j) {
        int r = r0 + orow + j;
        float v = acc[j] + xq_g[(size_t)r * IDIM + oc] + cb;
        xc[(size_t)r * IDIM + oc] = v;
        xcb[(size_t)r * IDIM + oc] = f2b(v);
    }
}

// ---------------------------------------------------------------------------
// k3: E = xc @ Wsg^T + bsg  (512x1536, K=512). Wave per 16x16 tile.
// ---------------------------------------------------------------------------
__global__ __launch_bounds__(256) void k3_mfma(const unsigned short* __restrict__ xcb,
                                               const unsigned short* __restrict__ Wsgb,
                                               const float* __restrict__ bsg,
                                               float* __restrict__ E) {
    const int t = threadIdx.x;
    const int w = blockIdx.x * 4 + (t >> 6);   // 0..3071
    const int lane = t & 63;
    const int mt = w / 96, nt = w % 96;
    const int r0 = mt * 16, j0 = nt * 16;
    const int fr = lane & 15, fk = (lane >> 4) * 8;
    const unsigned short* ap = xcb + (size_t)(r0 + fr) * IDIM + fk;
    const unsigned short* bp = Wsgb + (size_t)(j0 + fr) * IDIM + fk;
    f32x4 acc = {0.f, 0.f, 0.f, 0.f};
    #pragma unroll
    for (int k0 = 0; k0 < IDIM; k0 += 32) {
        bf16x8 av = *(const bf16x8*)(ap + k0);
        bf16x8 bv = *(const bf16x8*)(bp + k0);
        acc = __builtin_amdgcn_mfma_f32_16x16x32_bf16(av, bv, acc, 0, 0, 0);
    }
    const int orow = (lane >> 4) * 4;
    const int jc = j0 + fr;
    const float bias = bsg[jc];
    #pragma unroll
    for (int j = 0; j < 4; ++j)
        E[(size_t)(r0 + orow + j) * ESZ + jc] = acc[j] + bias;
}

// ---------------------------------------------------------------------------
// K3b: Cw[r,s] = sigmoid(E[r,1024+s]) * E[r,s];  u[r,i] = xc[r,i]*E[r,512+i]^2
// ---------------------------------------------------------------------------
__global__ __launch_bounds__(256) void k3b_elem(const float* __restrict__ E,
                                                const float* __restrict__ xc,
                                                float* __restrict__ Cw,
                                                float* __restrict__ u) {
    int idx4 = (blockIdx.x * 256 + threadIdx.x) * 4;  // < 512*512
    int r = idx4 >> 9, s = idx4 & 511;
    const float* Er = E + (size_t)r * ESZ;
    float4 craw = *(const float4*)&Er[s];
    float4 dw   = *(const float4*)&Er[512 + s];
    float4 graw = *(const float4*)&Er[1024 + s];
    float4 xcv  = *(const float4*)&xc[idx4];
    float4 cw, uv;
    cw.x = craw.x / (1.0f + expf(-graw.x));
    cw.y = craw.y / (1.0f + expf(-graw.y));
    cw.z = craw.z / (1.0f + expf(-graw.z));
    cw.w = craw.w / (1.0f + expf(-graw.w));
    uv.x = xcv.x * dw.x * dw.x;
    uv.y = xcv.y * dw.y * dw.y;
    uv.z = xcv.z * dw.z * dw.z;
    uv.w = xcv.w * dw.w * dw.w;
    *(float4*)&Cw[idx4] = cw;
    *(float4*)&u[idx4]  = uv;
}

// ---------------------------------------------------------------------------
// K4a: chunk-local scan from h=0; write chunk-final carry C_loc[b][c][i][s].
// ---------------------------------------------------------------------------
__global__ __launch_bounds__(256) void k4a_pass1(const float* __restrict__ u,
                                                 const float* __restrict__ A,
                                                 float* __restrict__ C_loc) {
    const int wave = (blockIdx.x * 256 + threadIdx.x) >> 6;  // 0..4095
    const int lane = threadIdx.x & 63;
    const int i = wave & 511;
    const int c = (wave >> 9) & (NC - 1);
    const int b = wave >> 11;
    const int s8 = lane * 8;
    float a[8], h[8];
    #pragma unroll
    for (int j = 0; j < 8; ++j) {
        a[j] = A[(size_t)(s8 + j) * IDIM + i];
        h[j] = 0.0f;
    }
    const float* ub = u + ((size_t)b * LSEQ + c * TCH) * IDIM;
    for (int l = 0; l < TCH; ++l) {
        float4 u0 = *(const float4*)(ub + l * IDIM + s8);
        float4 u1 = *(const float4*)(ub + l * IDIM + s8 + 4);
        h[0] = h[0] * a[0] + u0.x; h[1] = h[1] * a[1] + u0.y;
        h[2] = h[2] * a[2] + u0.z; h[3] = h[3] * a[3] + u0.w;
        h[4] = h[4] * a[4] + u1.x; h[5] = h[5] * a[5] + u1.y;
        h[6] = h[6] * a[6] + u1.z; h[7] = h[7] * a[7] + u1.w;
    }
    float* cp = C_loc + (((size_t)b * NC + c) * IDIM + i) * IDIM + s8;
    float4 v0, v1;
    v0.x = h[0]; v0.y = h[1]; v0.z = h[2]; v0.w = h[3];
    v1.x = h[4]; v1.y = h[5]; v1.z = h[6]; v1.w = h[7];
    *(float4*)cp = v0;
    *(float4*)(cp + 4) = v1;
}

// ---------------------------------------------------------------------------
// K4b: sequential combine over chunks: H[b][c] = state entering chunk c.
// ---------------------------------------------------------------------------
__global__ __launch_bounds__(256) void k4b_combine(const float* __restrict__ A,
                                                   const float* __restrict__ C_loc,
                                                   float* __restrict__ H) {
    int idx = blockIdx.x * 256 + threadIdx.x;   // < 2*512*128
    int s4 = (idx & 127) * 4;
    int i  = (idx >> 7) & 511;
    int b  = idx >> 16;
    float da[4], h4[4] = {0.0f, 0.0f, 0.0f, 0.0f};
    #pragma unroll
    for (int j = 0; j < 4; ++j) {
        float aa = A[(size_t)(s4 + j) * IDIM + i];
        aa = aa * aa; aa = aa * aa; aa = aa * aa;
        aa = aa * aa; aa = aa * aa; aa = aa * aa;   // ^64 == TCH
        da[j] = aa;
    }
    for (int c = 0; c < NC; ++c) {
        size_t base = (((size_t)b * NC + c) * IDIM + i) * IDIM + s4;
        float4 hv;
        hv.x = h4[0]; hv.y = h4[1]; hv.z = h4[2]; hv.w = h4[3];
        *(float4*)&H[base] = hv;
        float4 cl = *(const float4*)&C_loc[base];
        h4[0] = h4[0] * da[0] + cl.x;
        h4[1] = h4[1] * da[1] + cl.y;
        h4[2] = h4[2] * da[2] + cl.z;
        h4[3] = h4[3] * da[3] + cl.w;
    }
}

// ---------------------------------------------------------------------------
// K4c: seeded chunk scan + contraction; writes y as bf16 for MFMA k5a.
// ---------------------------------------------------------------------------
__global__ __launch_bounds__(256) void k4c_pass2(const float* __restrict__ u,
                                                 const float* __restrict__ Cw,
                                                 const float* __restrict__ A,
                                                 const float* __restrict__ D,
                                                 const float* __restrict__ H,
                                                 unsigned short* __restrict__ ybb) {
    const int wave = (blockIdx.x * 256 + threadIdx.x) >> 6;  // 0..4095
    const int lane = threadIdx.x & 63;
    const int i = wave & 511;
    const int c = (wave >> 9) & (NC - 1);
    const int b = wave >> 11;
    const int s8 = lane * 8;
    float a[8], h[8];
    #pragma unroll
    for (int j = 0; j < 8; ++j) a[j] = A[(size_t)(s8 + j) * IDIM + i];
    const float* hp = H + (((size_t)b * NC + c) * IDIM + i) * IDIM + s8;
    float4 h0v = *(const float4*)hp;
    float4 h1v = *(const float4*)(hp + 4);
    h[0] = h0v.x; h[1] = h0v.y; h[2] = h0v.z; h[3] = h0v.w;
    h[4] = h1v.x; h[5] = h1v.y; h[6] = h1v.z; h[7] = h1v.w;
    const float Di = D[i];
    const float* ub = u + (size_t)b * LSEQ * IDIM;
    const float* cb = Cw + (size_t)b * LSEQ * IDIM;
    unsigned short* yb = ybb + (size_t)b * LSEQ * IDIM;
    for (int l0 = c * TCH; l0 < c * TCH + TCH; l0 += 4) {
        float p[4];
        #pragma unroll
        for (int j = 0; j < 4; ++j) {
            const int l = l0 + j;
            const float4* up = (const float4*)(ub + l * IDIM + s8);
            const float4* cp = (const float4*)(cb + l * IDIM + s8);
            float4 u0 = up[0], u1 = up[1];
            float4 c0 = cp[0], c1 = cp[1];
            h[0] = h[0] * a[0] + u0.x; h[1] = h[1] * a[1] + u0.y;
            h[2] = h[2] * a[2] + u0.z; h[3] = h[3] * a[3] + u0.w;
            h[4] = h[4] * a[4] + u1.x; h[5] = h[5] * a[5] + u1.y;
            h[6] = h[6] * a[6] + u1.z; h[7] = h[7] * a[7] + u1.w;
            float p0 = c0.x * h[0] + c0.y * h[1] + c0.z * h[2] + c0.w * h[3];
            float p1 = c1.x * h[4] + c1.y * h[5] + c1.z * h[6] + c1.w * h[7];
            p[j] = p0 + p1;
        }
        #pragma unroll
        for (int off = 1; off < 64; off <<= 1) {
            #pragma unroll
            for (int j = 0; j < 4; ++j) p[j] += __shfl_xor(p[j], off, 64);
        }
        if (lane == 0) {
            #pragma unroll
            for (int j = 0; j < 4; ++j)
                yb[(l0 + j) * IDIM + i] = f2b(p[j] + ub[(l0 + j) * IDIM + i] * Di);
        }
    }
}

// ---------------------------------------------------------------------------
// k5a: outlin = y @ W_out^T (512x256, K=512). Wave per 16x16 tile.
// ---------------------------------------------------------------------------
__global__ __launch_bounds__(256) void k5a_mfma(const unsigned short* __restrict__ ybb,
                                                const unsigned short* __restrict__ W_outb,
                                                float* __restrict__ outlin) {
    const int t = threadIdx.x;
    const int w = blockIdx.x * 4 + (t >> 6);   // 0..511
    const int lane = t & 63;
    const int mt = w >> 4, nt = w & 15;
    const int r0 = mt * 16, h0 = nt * 16;
    const int fr = lane & 15, fk = (lane >> 4) * 8;
    const unsigned short* ap = ybb + (size_t)(r0 + fr) * IDIM + fk;
    const unsigned short* bp = W_outb + (size_t)(h0 + fr) * IDIM + fk;
    f32x4 acc = {0.f, 0.f, 0.f, 0.f};
    #pragma unroll
    for (int k0 = 0; k0 < IDIM; k0 += 32) {
        bf16x8 av = *(const bf16x8*)(ap + k0);
        bf16x8 bv = *(const bf16x8*)(bp + k0);
        acc = __builtin_amdgcn_mfma_f32_16x16x32_bf16(av, bv, acc, 0, 0, 0);
    }
    const int orow = (lane >> 4) * 4;
    const int hc = h0 + fr;
    #pragma unroll
    for (int j = 0; j < 4; ++j)
        outlin[(size_t)(r0 + orow + j) * HDIM + hc] = acc[j];
}

// ---------------------------------------------------------------------------
// K5b: LayerNorm over H=256 + z scale + residual. One block per row.
// ---------------------------------------------------------------------------
__global__ __launch_bounds__(256) void k5b_ln(const float* __restrict__ outlin,
                                              const float* __restrict__ x,
                                              const float* __restrict__ z,
                                              const float* __restrict__ ln_g,
                                              const float* __restrict__ ln_b,
                                              float* __restrict__ out) {
    const int r = blockIdx.x;
    const int t = threadIdx.x;
    float v = outlin[(size_t)r * HDIM + t];
    float s1 = v, s2 = v * v;
    #pragma unroll
    for (int off = 1; off < 64; off <<= 1) {
        s1 += __shfl_xor(s1, off, 64);
        s2 += __shfl_xor(s2, off, 64);
    }
    __shared__ float r1[4], r2[4];
    const int w = t >> 6, lane = t & 63;
    if (lane == 0) { r1[w] = s1; r2[w] = s2; }
    __syncthreads();
    float t1 = r1[0] + r1[1] + r1[2] + r1[3];
    float t2 = r2[0] + r2[1] + r2[2] + r2[3];
    float mu = t1 * (1.0f / 256.0f);
    float var = t2 * (1.0f / 256.0f) - mu * mu;
    float inv = rsqrtf(var + 1e-5f);
    float o = (v - mu) * inv * ln_g[t] + ln_b[t];
    out[(size_t)r * HDIM + t] = o * z[0] + x[(size_t)r * HDIM + t];
}

// ---------------------------------------------------------------------------
extern "C" void kernel_launch(void* const* d_in, const int* in_sizes, int n_in,
                              void* d_out, int out_size, void* d_ws, size_t ws_size,
                              hipStream_t stream) {
    const float* x      = (const float*)d_in[0];
    const float* W_in   = (const float*)d_in[1];
    const float* conv_w = (const float*)d_in[2];
    const float* conv_b = (const float*)d_in[3];
    const float* W_ssm  = (const float*)d_in[4];
    const float* b_ssm  = (const float*)d_in[5];
    const float* W_gate = (const float*)d_in[6];
    const float* b_gate = (const float*)d_in[7];
    const float* A      = (const float*)d_in[8];
    const float* D      = (const float*)d_in[9];
    const float* W_out  = (const float*)d_in[10];
    const float* z      = (const float*)d_in[11];
    const float* ln_g   = (const float*)d_in[12];
    const float* ln_b   = (const float*)d_in[13];
    float* out = (float*)d_out;

    float* ws = (float*)d_ws;
    float*          xq_g   = ws;                               // 262144 f32
    float*          xc     = ws + 262144;                      // 262144 f32
    float*          E      = ws + 524288;                      // 786432 f32
    float*          Cw     = ws + 1310720;                     // 262144 f32
    float*          u      = ws + 1572864;                     // 262144 f32
    float*          outlin = ws + 1835008;                     // 131072 f32
    float*          bsg    = ws + 1966080;                     // 2048 f32 (1536 used)
    unsigned short* xcb    = (unsigned short*)(ws + 1968128);  // 262144 bf16
    unsigned short* xkb    = (unsigned short*)(ws + 2099200);  // 262144 bf16
    unsigned short* Wsgb   = (unsigned short*)(ws + 2230272);  // 786432 bf16
    unsigned short* W_outb = (unsigned short*)(ws + 2623488);  // 131072 bf16
    unsigned short* ybb    = (unsigned short*)(ws + 2689024);  // 262144 bf16
    // AREA: {xb, Wb, cwb} dead after kxc; reused for {C_loc, H}
    float*          area   = ws + 2820096;                     // 4194304 f32
    unsigned short* xb     = (unsigned short*)area;            // 131072 bf16
    unsigned short* Wb     = (unsigned short*)(area + 65536);  // 262144 bf16
    unsigned short* cwb    = (unsigned short*)(area + 196608); // 786432 bf16
    float*          C_loc  = area;                             // 2097152 f32
    float*          Hbuf   = area + 2097152;                   // 2097152 f32

    kcvt      <<<512, 256, 0, stream>>>(x, W_in, conv_w, W_ssm, W_gate, b_ssm,
                                        b_gate, W_out, xb, Wb, cwb, Wsgb, bsg, W_outb);
    k1_mfma   <<<512, 256, 0, stream>>>(xb, Wb, xq_g, xkb);
    kxc_mfma  <<<256, 256, 0, stream>>>(xkb, cwb, xq_g, conv_b, xc, xcb);
    k3_mfma   <<<768, 256, 0, stream>>>(xcb, Wsgb, bsg, E);
    k3b_elem  <<<256, 256, 0, stream>>>(E, xc, Cw, u);
    k4a_pass1 <<<1024, 256, 0, stream>>>(u, A, C_loc);
    k4b_combine<<<512, 256, 0, stream>>>(A, C_loc, Hbuf);
    k4c_pass2 <<<1024, 256, 0, stream>>>(u, Cw, A, D, Hbuf, ybb);
    k5a_mfma  <<<128, 256, 0, stream>>>(ybb, W_outb, outlin);
    k5b_ln    <<<512, 256, 0, stream>>>(outlin, x, z, ln_g, ln_b, out);
}